// Round 11
// baseline (794.578 us; speedup 1.0000x reference)
//
#include <hip/hip_runtime.h>
#include <hip/hip_bf16.h>

#define HH 512
#define WW 512
#define NB 8
#define IMG (HH*WW)
#define TS 15
#define NTL 35   // ceil(511/15)+1 tiles cover rows 0..524

typedef __bf16 bf16x8 __attribute__((ext_vector_type(8)));
typedef float  f32x4  __attribute__((ext_vector_type(4)));

// ---------- bf16 helpers ----------
__device__ __forceinline__ float bflo(unsigned u){ return __uint_as_float(u << 16); }
__device__ __forceinline__ float bfhi(unsigned u){ return __uint_as_float(u & 0xffff0000u); }
__device__ __forceinline__ unsigned f2bf_bits(float f){
    union { float f; unsigned u; } v; v.f = f;
    return (v.u + 0x7fffu + ((v.u >> 16) & 1u)) >> 16;   // RNE, finite inputs only
}
__device__ __forceinline__ unsigned packbf(float lo, float hi){
    return f2bf_bits(lo) | (f2bf_bits(hi) << 16);
}
// single-instruction packed f32->bf16 (RNE)
__device__ __forceinline__ unsigned cvtpk(float lo, float hi){
    unsigned r;
    asm("v_cvt_pk_bf16_f32 %0, %1, %2" : "=v"(r) : "v"(lo), "v"(hi));
    return r;
}

// ---------- weight prep (round-6 version: NO norm fold) ----------
// wb: w2 [oc][ic][tap] -> frag [tap][ks][f][lane]: ic = ks*32+(l>>4)*8+j, oc = f*16+(l&15)
// wa: w1 [oc][k=27]    -> A-frag [mf][lane]:       oc = mf*16+(l&15), k = (l>>4)*8+j (k>=27 -> 0)
__global__ void prep_kernel(const float* __restrict__ w2, const float* __restrict__ w1,
                            uint4* __restrict__ wb, uint4* __restrict__ wa)
{
    int i = blockIdx.x * 256 + threadIdx.x;
    if (i < 9*2*4*64){
        int tap = i >> 9;
        int rem = i & 511;
        int ks  = rem >> 8;
        int nf  = (rem >> 6) & 3;
        int l   = rem & 63;
        int oc  = nf*16 + (l & 15);
        int icb = ks*32 + (l >> 4)*8;
        float v[8];
        #pragma unroll
        for (int j = 0; j < 8; ++j)
            v[j] = w2[(oc*64 + icb + j)*9 + tap];
        uint4 q;
        q.x = packbf(v[0], v[1]); q.y = packbf(v[2], v[3]);
        q.z = packbf(v[4], v[5]); q.w = packbf(v[6], v[7]);
        wb[i] = q;
    } else if (i < 9*2*4*64 + 4*64){
        int idx = i - 9*2*4*64;
        int mf = idx >> 6, l = idx & 63;
        int oc = mf*16 + (l & 15);
        int kb = (l >> 4)*8;
        float v[8];
        #pragma unroll
        for (int j = 0; j < 8; ++j)
            v[j] = (kb + j < 27) ? w1[oc*27 + kb + j] : 0.f;
        uint4 q;
        q.x = packbf(v[0], v[1]); q.y = packbf(v[2], v[3]);
        q.z = packbf(v[4], v[5]); q.w = packbf(v[6], v[7]);
        wa[idx] = q;
    }
}

// ---------- fused normalize + conv1(MFMA) + conv2(MFMA) + similarity maps ----------
// ROUND-6 PROVEN VERSION VERBATIM (diff-form sims, no hn, no dot2).
// LDS chunk-major SoA. 79 KB -> 2 blocks/CU.
__global__ __launch_bounds__(256, 2)
void conv_sims_kernel(const float* __restrict__ img,
                      const float* __restrict__ b1,
                      const uint4* __restrict__ wa,
                      const uint4* __restrict__ wb, const float* __restrict__ b2,
                      float* __restrict__ vs, float* __restrict__ hs)
{
    __shared__ float xs[3][20][20];
    __shared__ uint4 fs4[8*324];         // fs4[c*324 + px]
    __shared__ uint4 uni[2048];          // xi[c*336+px] (c 0..3) then ft[c*256+px] (c 0..7)

    const int tid = threadIdx.x;
    const int bid = blockIdx.x;
    const int b   = bid / (NTL*NTL);
    const int t2  = bid % (NTL*NTL);
    const int th  = t2 / NTL, tw = t2 % NTL;
    const int h0  = th * TS, w0 = tw * TS;

    // ---- phase 1: stage normalized input (zero outside image) ----
    for (int i = tid; i < 3*20*20; i += 256){
        int ic = i / 400, r = (i / 20) % 20, c = i % 20;
        int gy = h0 - 2 + r, gx = w0 - 2 + c;
        float mean = (ic == 0) ? 0.485f : (ic == 1) ? 0.456f : 0.406f;
        float istd = (ic == 0) ? (1.f/0.229f) : (ic == 1) ? (1.f/0.224f) : (1.f/0.225f);
        float v = 0.f;
        if (gy >= 0 && gy < HH && gx >= 0 && gx < WW)
            v = (img[(b*3 + ic)*IMG + gy*WW + gx] - mean) * istd;
        xs[ic][r][c] = v;
    }
    __syncthreads();

    // ---- phase 2a: im2col records xi[4][336] chunk-major ----
    {
        for (int p = tid; p < 336; p += 256){
            uint4 c0 = {0,0,0,0}, c1 = c0, c2 = c0, c3 = c0;
            if (p < 324){
                int fy = p / 18, fx = p % 18;
                float xv[27];
                #pragma unroll
                for (int ic = 0; ic < 3; ++ic)
                    #pragma unroll
                    for (int ky = 0; ky < 3; ++ky)
                        #pragma unroll
                        for (int kx = 0; kx < 3; ++kx)
                            xv[ic*9 + ky*3 + kx] = xs[ic][fy + ky][fx + kx];
                c0.x = cvtpk(xv[0], xv[1]);  c0.y = cvtpk(xv[2], xv[3]);
                c0.z = cvtpk(xv[4], xv[5]);  c0.w = cvtpk(xv[6], xv[7]);
                c1.x = cvtpk(xv[8], xv[9]);  c1.y = cvtpk(xv[10], xv[11]);
                c1.z = cvtpk(xv[12], xv[13]);c1.w = cvtpk(xv[14], xv[15]);
                c2.x = cvtpk(xv[16], xv[17]);c2.y = cvtpk(xv[18], xv[19]);
                c2.z = cvtpk(xv[20], xv[21]);c2.w = cvtpk(xv[22], xv[23]);
                c3.x = cvtpk(xv[24], xv[25]);c3.y = cvtpk(xv[26], 0.f);
            }
            uni[0*336 + p] = c0;
            uni[1*336 + p] = c1;
            uni[2*336 + p] = c2;
            uni[3*336 + p] = c3;
        }
    }
    __syncthreads();

    // ---- phase 2b: conv1 via MFMA. D[row=oc][col=pixel]; K=32 in one step. ----
    {
        const int l  = tid & 63, wv = tid >> 6;
        const int lr = l & 15,  kg = l >> 4;
        const bf16x8* wav = (const bf16x8*)wa;
        const bf16x8* xib = (const bf16x8*)uni;

        bf16x8 af[4];
        #pragma unroll
        for (int mf = 0; mf < 4; ++mf) af[mf] = wav[(mf << 6) + l];
        f32x4 binit[4];
        #pragma unroll
        for (int mf = 0; mf < 4; ++mf)
            binit[mf] = *(const f32x4*)(b1 + mf*16 + kg*4);

        for (int nb = wv; nb < 21; nb += 4){
            int px = nb*16 + lr;
            bf16x8 bf = xib[kg*336 + px];
            int fy = px / 18, fx = px % 18;
            int gy = h0 - 1 + fy, gx = w0 - 1 + fx;
            bool inimg = (px < 324) && gy >= 0 && gy < HH && gx >= 0 && gx < WW;
            #pragma unroll
            for (int mf = 0; mf < 4; ++mf){
                f32x4 acc = __builtin_amdgcn_mfma_f32_16x16x32_bf16(af[mf], bf, binit[mf], 0, 0, 0);
                unsigned lo = 0, hi = 0;
                if (inimg){
                    lo = cvtpk(fmaxf(acc[0], 0.f), fmaxf(acc[1], 0.f));
                    hi = cvtpk(fmaxf(acc[2], 0.f), fmaxf(acc[3], 0.f));
                }
                if (px < 324){
                    char* p8 = (char*)fs4 + (((mf*2 + (kg >> 1)) * 324 + px) << 4) + ((kg & 1) << 3);
                    uint2 w2v; w2v.x = lo; w2v.y = hi;
                    *(uint2*)p8 = w2v;
                }
            }
        }
    }
    __syncthreads();

    // ---- phase 3: conv2 (64->64) via MFMA. A=weights (row=oc), B=pixel records (col=px). ----
    {
        const int wv = tid >> 6;
        const int l  = tid & 63;
        const int lr = l & 15;      // B/D col (px)
        const int kg = l >> 4;

        f32x4 acc[4][4];
        #pragma unroll
        for (int mf = 0; mf < 4; ++mf){
            f32x4 bv = *(const f32x4*)(b2 + mf*16 + kg*4);
            #pragma unroll
            for (int nf = 0; nf < 4; ++nf) acc[mf][nf] = bv;
        }

        const bf16x8* fsb = (const bf16x8*)fs4;
        const bf16x8* wbv = (const bf16x8*)wb;

        #pragma unroll
        for (int tap = 0; tap < 9; ++tap){
            const int dy = tap / 3, dx = tap % 3;
            #pragma unroll
            for (int ks = 0; ks < 2; ++ks){
                bf16x8 wfr[4];
                #pragma unroll
                for (int mf = 0; mf < 4; ++mf)
                    wfr[mf] = wbv[((tap*8 + ks*4 + mf) << 6) + l];
                #pragma unroll
                for (int nf = 0; nf < 4; ++nf){
                    int fpx = (wv*4 + nf + dy)*18 + lr + dx;
                    bf16x8 bfr = fsb[(ks*4 + kg)*324 + fpx];
                    #pragma unroll
                    for (int mf = 0; mf < 4; ++mf)
                        acc[mf][nf] = __builtin_amdgcn_mfma_f32_16x16x32_bf16(
                            wfr[mf], bfr, acc[mf][nf], 0, 0, 0);
                }
            }
        }

        // write ft (relu, bf16, chunk-major) with packed b64 stores  (round-6 epilogue)
        char* ftb = (char*)uni;
        #pragma unroll
        for (int nf = 0; nf < 4; ++nf){
            int px = wv*64 + nf*16 + lr;
            #pragma unroll
            for (int mf = 0; mf < 4; ++mf){
                uint2 wv2;
                wv2.x = cvtpk(fmaxf(acc[mf][nf][0], 0.f), fmaxf(acc[mf][nf][1], 0.f));
                wv2.y = cvtpk(fmaxf(acc[mf][nf][2], 0.f), fmaxf(acc[mf][nf][3], 0.f));
                *(uint2*)(ftb + (((mf*2 + (kg >> 1)) * 256 + px) << 4) + ((kg & 1) << 3)) = wv2;
            }
        }
    }
    __syncthreads();

    // ---- phase 4: similarity maps, DIFF-FORM (round-6 proven) ----
    const uint4* ft4 = uni;
    for (int s = tid; s < 450; s += 256){
        bool isv = (s < 225);
        int r  = isv ? s : (s - 225);
        int sy = r / 15, sx = r % 15;
        int gh = h0 + sy, gw = w0 + sx;
        if (gh >= HH || gw >= WW) continue;
        int pa = sy*16 + sx;
        int pb = isv ? (pa + 16) : (pa + 1);
        float ssd = 0.f;
        #pragma unroll
        for (int j = 0; j < 8; ++j){
            uint4 qa = ft4[j*256 + pa], qb = ft4[j*256 + pb];
            unsigned da[4] = {qa.x, qa.y, qa.z, qa.w};
            unsigned db[4] = {qb.x, qb.y, qb.z, qb.w};
            #pragma unroll
            for (int k = 0; k < 4; ++k){
                float d0 = bflo(da[k]) - bflo(db[k]);
                float d1 = bfhi(da[k]) - bfhi(db[k]);
                ssd = fmaf(d0, d0, ssd);
                ssd = fmaf(d1, d1, ssd);
            }
        }
        float sim = __expf(ssd * (-1.f/500.f));
        int o = b*IMG + gh*WW + gw;
        if (isv) vs[o] = (gh < HH-1) ? sim : 0.f;
        else     hs[o] = (gw < WW-1) ? sim : 0.f;
    }
}

// ---------- fused erode + 10-iteration Jacobi propagation + final output ----------
// 64x64 tile, halo 10; only cur in LDS; sims/mask from global (L2-resident).
__global__ __launch_bounds__(256, 4)
void prop10_kernel(const float* __restrict__ vsg, const float* __restrict__ hsg,
                   const float* __restrict__ mask, float* __restrict__ dout)
{
    __shared__ float cu[86*88];

    const int tid = threadIdx.x;
    const int bid = blockIdx.x;                 // 512 = b(8) x ty(8) x tx(8)
    const int b  = bid >> 6;
    const int ty = (bid >> 3) & 7, tx = bid & 7;
    const int gyc = ty*64, gxc = tx*64;
    const int gy0m = gyc - 11, gx0m = gxc - 11; // cu[ly][lx] = mask(gy0m+ly, gx0m+lx)
    const float* mb = mask + b*IMG;
    const float* vb = vsg + b*IMG;
    const float* hb = hsg + b*IMG;

    // stage mask halo-11 (zero outside image)
    for (int i = tid; i < 86*86; i += 256){
        int ly = i / 86, lx = i % 86;
        int gy = gy0m + ly, gx = gx0m + lx;
        float v = 0.f;
        if (gy >= 0 && gy < HH && gx >= 0 && gx < WW) v = mb[gy*WW + gx];
        cu[ly*88 + lx] = v;
    }
    __syncthreads();

    // erode over halo-10 region (84x84): cur0 = (3x3 sum > 1) ? 0 : 1
    float val[28];
    #pragma unroll
    for (int i = 0; i < 28; ++i){
        int px = tid + i*256;
        if (px < 84*84){
            int j = px / 84, x = px % 84;
            int o = j*88 + x;
            float s = cu[o]     + cu[o+1]   + cu[o+2]
                    + cu[o+88]  + cu[o+89]  + cu[o+90]
                    + cu[o+176] + cu[o+177] + cu[o+178];
            val[i] = (s > 1.f) ? 0.f : 1.f;
        }
    }
    __syncthreads();
    #pragma unroll
    for (int i = 0; i < 28; ++i){
        int px = tid + i*256;
        if (px < 84*84){
            int j = px / 84, x = px % 84;
            int gy = gyc - 10 + j, gx = gxc - 10 + x;
            if (gy >= 0 && gy < HH && gx >= 0 && gx < WW)
                cu[(j+1)*88 + (x+1)] = val[i];
        }
    }
    __syncthreads();
    // clamp-fill out-of-image halo cells from their clamped in-image cells
    for (int i = tid; i < 84*84; i += 256){
        int j = i / 84, x = i % 84;
        int gy = gyc - 10 + j, gx = gxc - 10 + x;
        if (gy < 0 || gy >= HH || gx < 0 || gx >= WW){
            int cj = min(max(gy, 0), 511) - (gyc - 10);
            int cx = min(max(gx, 0), 511) - (gxc - 10);
            cu[(j+1)*88 + (x+1)] = cu[(cj+1)*88 + (cx+1)];
        }
    }
    __syncthreads();

    // 10 Jacobi iterations over shrinking halo; sims from global (L2)
    for (int k = 1; k <= 10; ++k){
        #pragma unroll
        for (int i = 0; i < 28; ++i){
            int px = tid + i*256;
            if (px < 84*84){
                int j = px / 84, x = px % 84;
                bool act = (j >= k) && (j < 84-k) && (x >= k) && (x < 84-k);
                if (act){
                    int o = (j+1)*88 + (x+1);
                    int gy = gyc - 10 + j, gx = gxc - 10 + x;
                    int cgy  = min(max(gy, 0), 511),  cgym = min(max(gy-1, 0), 511);
                    int cgx  = min(max(gx, 0), 511),  cgxm = min(max(gx-1, 0), 511);
                    float c  = cu[o];
                    float tp = cu[o-88] * vb[cgym*WW + cgx];
                    float bt = cu[o+88] * vb[cgy *WW + cgx];
                    float lf = cu[o-1]  * hb[cgy *WW + cgxm];
                    float rg = cu[o+1]  * hb[cgy *WW + cgx];
                    val[i] = fmaxf(fmaxf(c, fmaxf(tp, bt)), fmaxf(lf, rg));
                }
            }
        }
        __syncthreads();
        #pragma unroll
        for (int i = 0; i < 28; ++i){
            int px = tid + i*256;
            if (px < 84*84){
                int j = px / 84, x = px % 84;
                bool act = (j >= k) && (j < 84-k) && (x >= k) && (x < 84-k);
                if (act) cu[(j+1)*88 + (x+1)] = val[i];
            }
        }
        __syncthreads();
    }

    // final: out = min(mask, 1 - cur) on the 64x64 interior
    for (int i = tid; i < 64*64; i += 256){
        int y = i >> 6, x = i & 63;
        float v = cu[(y + 11)*88 + (x + 11)];
        int g = b*IMG + (gyc + y)*WW + (gxc + x);
        dout[g] = fminf(mb[(gyc + y)*WW + (gxc + x)], 1.f - v);
    }
}

extern "C" void kernel_launch(void* const* d_in, const int* in_sizes, int n_in,
                              void* d_out, int out_size, void* d_ws, size_t ws_size,
                              hipStream_t stream)
{
    const float* img  = (const float*)d_in[0];
    // d_in[1] (pred_img) unused by the reference.
    const float* mask = (const float*)d_in[2];
    const float* w1   = (const float*)d_in[3];
    const float* b1   = (const float*)d_in[4];
    const float* w2   = (const float*)d_in[5];
    const float* b2   = (const float*)d_in[6];
    float* out = (float*)d_out;

    float* vs    = (float*)d_ws;            // [8][512][512]
    float* hsm   = vs + NB*IMG;             // [8][512][512]
    uint4* wbuf  = (uint4*)(hsm + NB*IMG);  // [4608] conv2 A-frags
    uint4* wabuf = wbuf + 4608;             // [256]  conv1 A-frags

    prep_kernel<<<19, 256, 0, stream>>>(w2, w1, wbuf, wabuf);
    conv_sims_kernel<<<NB*NTL*NTL, 256, 0, stream>>>(img, b1, wabuf, wbuf, b2, vs, hsm);
    prop10_kernel<<<512, 256, 0, stream>>>(vs, hsm, mask, out);
}